// Round 12
// baseline (175.371 us; speedup 1.0000x reference)
//
#include <hip/hip_runtime.h>
#include <hip/hip_bf16.h>
#include <math.h>

constexpr int B_  = 16;
constexpr int C_  = 1536;
constexpr int T_  = 2000;
constexpr int H_  = 128;
constexpr int C3_ = 3 * C_;   // 4608
constexpr int C2_ = 2 * C_;   // 3072
constexpr int NT_ = 4;        // t-parts for gemm2 (512 t each)
constexpr int NTL_ = 32;      // gemm1 t-tiles (64 t each)
constexpr int KH_ = C_ / 2;   // gemm1 K-half (768)
constexpr int NG1_ = NTL_ * B_ * 2;      // 1024 gemm1 blocks
constexpr int NST_ = B_ * C_ / 4;        // 6144 stats blocks (4 rows each)

typedef short bf8 __attribute__((ext_vector_type(8)));   // 8 bf16 (4 VGPR) MFMA A/B frag
typedef short bf4 __attribute__((ext_vector_type(4)));   // 4 bf16 (8B)
typedef float f4  __attribute__((ext_vector_type(4)));   // MFMA C/D frag

// fp32 -> bf16 RTNE (hardware cvt; compiler pairs into v_cvt_pk_bf16_f32)
__device__ inline unsigned short f2b(float f) {
  __bf16 h = (__bf16)f;
  return __builtin_bit_cast(unsigned short, h);
}

// ---------------- K1: gemm1 (MFMA, K-split x2) ∥ stats, role-interleaved ------
// grid 7*1024 blocks; blockIdx%7==0 -> gemm1 block (1024), else stats (6144).
// The two roles are INDEPENDENT (gemm1 writes raw h_pre; hconst applied in
// ln_epi), so interleaving them overlaps stats' pure-HBM phase with gemm1's
// DS/VALU-heavy phase. gemm1 inner loop carries NO stats work (R9-R11 fused
// 16 shuffles/step into it -- that was the hidden +29us).
__global__ __launch_bounds__(256) void k_g1_and_stats(
    const float* __restrict__ x, const float* __restrict__ w1,
    const float* __restrict__ mask,
    float* __restrict__ h_pre, float* __restrict__ mean0, float* __restrict__ std0) {
  __shared__ __align__(16) short As[2][128 * 32];
  __shared__ __align__(16) short Bs[2][64 * 32];
  const int tid = threadIdx.x;
  const int gid = blockIdx.x / 7;
  const int rem = blockIdx.x % 7;

  if (rem != 0) {
    // ---- stats role: one wave per (b,c) row, direct mean0/std0 ----
    const int sid = gid * 6 + rem - 1;          // 0..6143
    const int wave = tid >> 6;
    const int lane = tid & 63;
    const int row = sid * 4 + wave;             // b*C + c
    const int b = row / C_;
    const float4* xr = (const float4*)(x + (size_t)row * T_);
    const float4* mr = (const float4*)(mask + (size_t)b * T_);
    float sm = 0.f, s1 = 0.f, s2 = 0.f;
    for (int i = lane; i < T_ / 4; i += 64) {
      float4 xv = xr[i];
      float4 mv = mr[i];
      sm += mv.x + mv.y + mv.z + mv.w;
      s1 += mv.x * xv.x + mv.y * xv.y + mv.z * xv.z + mv.w * xv.w;
      s2 += mv.x * xv.x * xv.x + mv.y * xv.y * xv.y + mv.z * xv.z * xv.z + mv.w * xv.w * xv.w;
    }
#pragma unroll
    for (int off = 32; off; off >>= 1) {
      sm += __shfl_xor(sm, off);
      s1 += __shfl_xor(s1, off);
      s2 += __shfl_xor(s2, off);
    }
    if (lane == 0) {
      float mean = s1 / sm;
      float var = s2 / sm - mean * mean;
      mean0[row] = mean;
      std0[row] = sqrtf(fmaxf(var, 1e-5f));
    }
    return;
  }

  // ---- gemm1 role: tile 128h x 64t, K-half z ----
  const int tile = gid & 31;
  const int b = (gid >> 5) & 15;
  const int kbase = (gid >> 9) * KH_;
  const int t0 = tile * 64;
  const int lane = tid & 63;
  const int w = tid >> 6;
  const int l15 = lane & 15;
  const int l4 = lane >> 4;
  const int tl = tid & 63;      // B-staging: this thread's t-column
  const int kq = tid >> 6;      // B-staging: this thread's 8-k group

  float4 va[4];
  float xs[8];

  f4 acc[8];
#pragma unroll
  for (int mi = 0; mi < 8; ++mi) { f4 z = {0.f, 0.f, 0.f, 0.f}; acc[mi] = z; }

// A: 4x float4 of w1 rows; B: 8 coalesced dword loads of one t-column,
// 8 consecutive k (256B/wave per load) -- replaces R11's strided float4 path.
#define G1_GLOAD(K0)                                                          \
  {                                                                           \
    _Pragma("unroll")                                                         \
    for (int q = 0; q < 4; ++q) {                                             \
      int idx = q * 256 + tid;                                                \
      int row = idx >> 3, j4 = idx & 7;                                       \
      va[q] = *(const float4*)(w1 + (size_t)row * C3_ + (K0) + j4 * 4);       \
    }                                                                         \
    {                                                                         \
      int t = t0 + tl;                                                        \
      const float* xb = x + ((size_t)(b * C_ + (K0) + kq * 8)) * T_ + t;      \
      if (t < T_) {                                                           \
        _Pragma("unroll")                                                     \
        for (int j = 0; j < 8; ++j) xs[j] = xb[(size_t)j * T_];               \
      } else {                                                                \
        _Pragma("unroll")                                                     \
        for (int j = 0; j < 8; ++j) xs[j] = 0.f;                              \
      }                                                                       \
    }                                                                         \
  }
// A: 4x bf4 writes (as before). B: ONE ds_write_b128 of 8 k-contiguous bf16
// at slot = kq ^ ((t>>2)&3), matching the read swizzle l4 ^ ((l15>>2)&3).
#define G1_LSTORE(BUF)                                                        \
  {                                                                           \
    _Pragma("unroll")                                                         \
    for (int q = 0; q < 4; ++q) {                                             \
      int idx = q * 256 + tid;                                                \
      int row = idx >> 3, j4 = idx & 7;                                       \
      int slot = (j4 >> 1) ^ ((row >> 2) & 3);                                \
      bf4 p;                                                                  \
      p[0] = (short)f2b(va[q].x); p[1] = (short)f2b(va[q].y);                 \
      p[2] = (short)f2b(va[q].z); p[3] = (short)f2b(va[q].w);                 \
      *(bf4*)&As[BUF][row * 32 + slot * 8 + (j4 & 1) * 4] = p;                \
    }                                                                         \
    {                                                                         \
      bf8 p;                                                                  \
      _Pragma("unroll")                                                       \
      for (int j = 0; j < 8; ++j) p[j] = (short)f2b(xs[j]);                   \
      *(bf8*)&Bs[BUF][tl * 32 + (kq ^ ((tl >> 2) & 3)) * 8] = p;              \
    }                                                                         \
  }

  G1_GLOAD(kbase);
  G1_LSTORE(0);
  __syncthreads();

  const int fA = (l15 >> 2) & 3;        // row-swizzle term, mi/w-independent
  const int NS = KH_ / 32;              // 24 K-steps per half
  for (int s = 0; s < NS; ++s) {
    const int cur = s & 1;
    if (s + 1 < NS) G1_GLOAD(kbase + (s + 1) * 32);
    {
      const int browB = w * 16 + l15;
      bf8 bfr = *(const bf8*)&Bs[cur][browB * 32 + (l4 ^ fA) * 8];
#pragma unroll
      for (int mi = 0; mi < 8; ++mi) {
        bf8 afr = *(const bf8*)&As[cur][(mi * 16 + l15) * 32 + (l4 ^ fA) * 8];
        acc[mi] = __builtin_amdgcn_mfma_f32_16x16x32_bf16(afr, bfr, acc[mi], 0, 0, 0);
      }
    }
    if (s + 1 < NS) G1_LSTORE(cur ^ 1);
    __syncthreads();
  }

  // store partial acc as fp32 h_pre[khalf][b][t][h]
  const int t = t0 + w * 16 + l15;
  if (t < T_) {
    float* dst = h_pre + (size_t)(gid >> 9) * B_ * T_ * H_ + ((size_t)b * T_ + t) * H_;
#pragma unroll
    for (int mi = 0; mi < 8; ++mi)
      *(f4*)&dst[mi * 16 + l4 * 4] = acc[mi];
  }
}

// ---------------- K2: hconst GEMV + wl1 L1-norms in ONE launch ----------------
__global__ __launch_bounds__(256) void k_hconst_wl1(
    const float* __restrict__ w1, const float* __restrict__ b1,
    const float* __restrict__ mean0, const float* __restrict__ std0,
    const float* __restrict__ w2,
    float* __restrict__ hconst, float* __restrict__ wl1) {
  const int wave = threadIdx.x >> 6;
  const int lane = threadIdx.x & 63;
  if (blockIdx.x < B_ * H_ / 4) {
    const int idx = blockIdx.x * 4 + wave;      // b*H + h
    const int b = idx >> 7;
    const int h = idx & (H_ - 1);
    const float* wm  = w1 + (size_t)h * C3_ + C_;
    const float* wsd = wm + C_;
    const float* mn = mean0 + b * C_;
    const float* sd = std0 + b * C_;
    float s = 0.f;
    for (int c = lane; c < C_; c += 64)
      s += wm[c] * mn[c] + wsd[c] * sd[c];
#pragma unroll
    for (int off = 32; off; off >>= 1) s += __shfl_xor(s, off);
    if (lane == 0) hconst[idx] = s + b1[h];
  } else {
    const int c = (blockIdx.x - B_ * H_ / 4) * 4 + wave;
    const float* wr = w2 + (size_t)c * H_;
    float s = fabsf(wr[lane]) + fabsf(wr[lane + 64]);
#pragma unroll
    for (int off = 32; off; off >>= 1) s += __shfl_xor(s, off);
    if (lane == 0) wl1[c] = s;
  }
}

// ---------------- K3: LN epilogue: h_preA+h_preB+hconst -> relu/LN/tanh -------
// grid (32 t-tiles, B); 256 thr = 64 t x 4 parts; part owns 32 h of one t.
__global__ __launch_bounds__(256) void k_ln_epi(
    const float* __restrict__ h_pre, const float* __restrict__ hconst,
    const float* __restrict__ g1, const float* __restrict__ be1,
    unsigned short* __restrict__ hlnT) {
  const int b = blockIdx.y;
  const int t = blockIdx.x * 64 + (threadIdx.x >> 2);
  const int part = threadIdx.x & 3;
  if (t >= T_) return;
  const float* srcA = h_pre + ((size_t)b * T_ + t) * H_ + part * 32;
  const float* srcB = srcA + (size_t)B_ * T_ * H_;
  const float* hc = hconst + b * H_ + part * 32;
  float v[32];
  float sum = 0.f, ssq = 0.f;
#pragma unroll
  for (int j = 0; j < 8; ++j) {
    float4 hA = *(const float4*)(srcA + j * 4);
    float4 hB = *(const float4*)(srcB + j * 4);
    float4 c4 = *(const float4*)(hc + j * 4);
    const float* pa = (const float*)&hA;
    const float* pb = (const float*)&hB;
    const float* cp = (const float*)&c4;
#pragma unroll
    for (int r = 0; r < 4; ++r) {
      float u = fmaxf(pa[r] + pb[r] + cp[r], 0.f);
      v[j * 4 + r] = u;
      sum += u;
      ssq += u * u;
    }
  }
  // reduce over the 4 parts (consecutive lanes)
  sum += __shfl_xor(sum, 1); sum += __shfl_xor(sum, 2);
  ssq += __shfl_xor(ssq, 1); ssq += __shfl_xor(ssq, 2);
  const float mean = sum * (1.f / 128.f);
  const float rstd = rsqrtf(ssq * (1.f / 128.f) - mean * mean + 1e-5f);
  unsigned short* dst = hlnT + ((size_t)b * T_ + t) * H_ + part * 32;
  const float* gp = g1 + part * 32;
  const float* ep = be1 + part * 32;
#pragma unroll
  for (int m = 0; m < 4; ++m) {
    bf8 p;
#pragma unroll
    for (int r = 0; r < 8; ++r) {
      int j = m * 8 + r;
      p[r] = (short)f2b(tanhf((v[j] - mean) * rstd * gp[j] + ep[j]));
    }
    *(bf8*)&dst[m * 8] = p;
  }
}

// ---------------- K4: MFMA GEMM2 (alpha=w2@hln) + FIXED-MAX softmax + pooling -
// grid (24 c-tiles of 64, B, NT parts); part owns t in [part*512, +512).
// A-operand (w2 rows) in REGISTERS; LDS = Hs 32KB only.
// e = exp(alpha - wl1[c]): no running max, no rescale; Mc cancels in s1/s0.
__global__ __launch_bounds__(256) void k_gemm2_pool(
    const float* __restrict__ x, const float* __restrict__ mask,
    const float* __restrict__ w2, const unsigned short* __restrict__ hlnT,
    const float* __restrict__ wl1,
    float* __restrict__ ps0, float* __restrict__ ps1, float* __restrict__ ps2) {
  __shared__ __align__(16) short Hs[2][64 * 128];   // [t][h] swizzled, 2x16KB
  const int b = blockIdx.y;
  const int c0 = blockIdx.x * 64;
  const int part = blockIdx.z;
  const int tb = part * 512;
  const int te = min(tb + 512, T_);
  const int tid = threadIdx.x;
  const int lane = tid & 63;
  const int w = tid >> 6;
  const int l15 = lane & 15;
  const int l4 = lane >> 4;

  // A-frags in registers: af[ks] = w2[c0+w*16+l15][(ks*4+l4)*8 ..+8]
  bf8 af[4];
#pragma unroll
  for (int ks = 0; ks < 4; ++ks) {
    const float* src = w2 + (size_t)(c0 + w * 16 + l15) * H_ + (ks * 4 + l4) * 8;
    float4 v0 = *(const float4*)src;
    float4 v1 = *(const float4*)(src + 4);
    bf8 p;
    p[0] = (short)f2b(v0.x); p[1] = (short)f2b(v0.y);
    p[2] = (short)f2b(v0.z); p[3] = (short)f2b(v0.w);
    p[4] = (short)f2b(v1.x); p[5] = (short)f2b(v1.y);
    p[6] = (short)f2b(v1.z); p[7] = (short)f2b(v1.w);
    af[ks] = p;
  }

  // static per-row logit bound Mc (exp arg <= 0, never overflows)
  float Mc[4];
  {
    float4 m4 = *(const float4*)(wl1 + c0 + w * 16 + l4 * 4);
    Mc[0] = m4.x; Mc[1] = m4.y; Mc[2] = m4.z; Mc[3] = m4.w;
  }

  float s0[4], s1[4], s2[4];
#pragma unroll
  for (int r = 0; r < 4; ++r) { s0[r] = 0.f; s1[r] = 0.f; s2[r] = 0.f; }

  bf8 hreg[4];
#define G2_HLOAD(T0)                                                          \
  {                                                                           \
    _Pragma("unroll")                                                         \
    for (int q = 0; q < 4; ++q) {                                             \
      int idx = q * 256 + tid;                                                \
      int row = idx >> 4, slot = idx & 15;                                    \
      int t = (T0) + row;                                                     \
      if (t > T_ - 1) t = T_ - 1;                                             \
      hreg[q] = *(const bf8*)(hlnT + ((size_t)b * T_ + t) * H_ + slot * 8);   \
    }                                                                         \
  }
#define G2_HSTORE(BUF)                                                        \
  {                                                                           \
    _Pragma("unroll")                                                         \
    for (int q = 0; q < 4; ++q) {                                             \
      int idx = q * 256 + tid;                                                \
      int row = idx >> 4, slot = idx & 15;                                    \
      *(bf8*)&Hs[BUF][row * 128 + (slot ^ (row & 15)) * 8] = hreg[q];         \
    }                                                                         \
  }

  G2_HLOAD(tb);
  G2_HSTORE(0);
  __syncthreads();

  const int NCH = (te - tb + 63) / 64;   // <= 8
  for (int ch = 0; ch < NCH; ++ch) {
    const int t0 = tb + ch * 64;
    const int cur = ch & 1;
    if (ch + 1 < NCH) G2_HLOAD(t0 + 64);

    // issue-early: mask + x loads for this chunk, consumed after MFMA
    float mk[4];
    int tcol[4];
#pragma unroll
    for (int nj = 0; nj < 4; ++nj) {
      int t = t0 + nj * 16 + l15;
      tcol[nj] = (t < T_) ? t : (T_ - 1);
      mk[nj] = (t < T_) ? mask[(size_t)b * T_ + t] : 0.f;
    }
    float xv[4][4];
#pragma unroll
    for (int reg = 0; reg < 4; ++reg) {
      const int c = c0 + w * 16 + l4 * 4 + reg;
      const float* xrow = x + ((size_t)(b * C_ + c)) * T_;
#pragma unroll
      for (int nj = 0; nj < 4; ++nj) xv[reg][nj] = xrow[tcol[nj]];
    }

    f4 acc[4];
#pragma unroll
    for (int nj = 0; nj < 4; ++nj) { f4 z = {0.f, 0.f, 0.f, 0.f}; acc[nj] = z; }

#pragma unroll
    for (int ks = 0; ks < 4; ++ks) {
      const int sw = (ks * 4 + l4) ^ l15;   // row&15 == l15 for B rows
      bf8 bb[4];
#pragma unroll
      for (int nj = 0; nj < 4; ++nj)
        bb[nj] = *(const bf8*)&Hs[cur][(nj * 16 + l15) * 128 + sw * 8];
#pragma unroll
      for (int nj = 0; nj < 4; ++nj)
        acc[nj] = __builtin_amdgcn_mfma_f32_16x16x32_bf16(af[ks], bb[nj], acc[nj], 0, 0, 0);
    }

    // epilogue: fixed-max exp + pooled partial sums (no serial chain)
#pragma unroll
    for (int reg = 0; reg < 4; ++reg) {
      float a0 = s0[reg], a1 = s1[reg], a2 = s2[reg];
#pragma unroll
      for (int nj = 0; nj < 4; ++nj) {
        float e = (mk[nj] != 0.f) ? __expf(acc[nj][reg] - Mc[reg]) : 0.f;
        float xvv = xv[reg][nj];
        a0 += e; a1 += e * xvv; a2 += e * xvv * xvv;
      }
      s0[reg] = a0; s1[reg] = a1; s2[reg] = a2;
    }

    // HSTORE after the epilogue: the epilogue VALU hides this iter's HLOAD
    // latency; buffer cur^1 was drained at the previous iteration's barrier.
    if (ch + 1 < NCH) G2_HSTORE(cur ^ 1);
    __syncthreads();
  }

  // merge the 16 lanes (t-cols) of each row group: plain adds
#pragma unroll
  for (int off = 1; off < 16; off <<= 1) {
#pragma unroll
    for (int r = 0; r < 4; ++r) {
      s0[r] += __shfl_xor(s0[r], off);
      s1[r] += __shfl_xor(s1[r], off);
      s2[r] += __shfl_xor(s2[r], off);
    }
  }
  if (l15 == 0) {
#pragma unroll
    for (int reg = 0; reg < 4; ++reg) {
      const int c = c0 + w * 16 + l4 * 4 + reg;
      const size_t j = ((size_t)(b * NT_ + part)) * C_ + c;
      ps0[j] = s0[reg]; ps1[j] = s1[reg]; ps2[j] = s2[reg];
    }
  }
}

// ---------------- K4b: plain-sum the NT t-part partials -> pooled -------------
__global__ __launch_bounds__(256) void k_pool_merge(
    const float* __restrict__ ps0, const float* __restrict__ ps1,
    const float* __restrict__ ps2, float* __restrict__ pooled) {
  const int idx = blockIdx.x * 256 + threadIdx.x;   // b*C + c
  const int b = idx / C_;
  const int c = idx - b * C_;
  float s0 = 0.f, s1 = 0.f, s2 = 0.f;
#pragma unroll
  for (int p = 0; p < NT_; ++p) {
    const size_t j = ((size_t)(b * NT_ + p)) * C_ + c;
    s0 += ps0[j]; s1 += ps1[j]; s2 += ps2[j];
  }
  float mean = s1 / s0;
  float var = s2 / s0 - mean * mean;
  pooled[b * C2_ + c] = mean;
  pooled[b * C2_ + C_ + c] = sqrtf(fmaxf(var, 1e-5f));
}

// ---------------- K5: final LN over 2C channels per b -------------------------
__global__ __launch_bounds__(256) void k_final_ln(
    const float* __restrict__ pooled, const float* __restrict__ g2,
    const float* __restrict__ be2, float* __restrict__ out) {
  __shared__ float rs[8];
  const int b = blockIdx.x;
  const int tid = threadIdx.x;
  const int lane = tid & 63;
  const int wave = tid >> 6;
  const float* p = pooled + b * C2_;
  float s = 0.f, q = 0.f;
  for (int i = tid; i < C2_; i += 256) {
    float v = p[i];
    s += v;
    q += v * v;
  }
#pragma unroll
  for (int off = 32; off; off >>= 1) {
    s += __shfl_xor(s, off);
    q += __shfl_xor(q, off);
  }
  if (lane == 0) { rs[wave] = s; rs[4 + wave] = q; }
  __syncthreads();
  s = rs[0] + rs[1] + rs[2] + rs[3];
  q = rs[4] + rs[5] + rs[6] + rs[7];
  float mean = s * (1.f / C2_);
  float var = q * (1.f / C2_) - mean * mean;
  float rstd = rsqrtf(var + 1e-5f);
  for (int i = tid; i < C2_; i += 256)
    out[b * C2_ + i] = (p[i] - mean) * rstd * g2[i] + be2[i];
}

extern "C" void kernel_launch(void* const* d_in, const int* in_sizes, int n_in,
                              void* d_out, int out_size, void* d_ws, size_t ws_size,
                              hipStream_t stream) {
  const float* x    = (const float*)d_in[0];
  const float* mask = (const float*)d_in[1];
  const float* w1   = (const float*)d_in[2];
  const float* b1   = (const float*)d_in[3];
  const float* g1   = (const float*)d_in[4];
  const float* be1  = (const float*)d_in[5];
  const float* w2   = (const float*)d_in[6];
  // d_in[7] = b2: per-(b,c) constant on softmax logits -> softmax-invariant, dropped
  const float* g2   = (const float*)d_in[8];
  const float* be2  = (const float*)d_in[9];
  float* out = (float*)d_out;

  float* ws     = (float*)d_ws;
  float* mean0  = ws;                   // B*C
  float* std0   = mean0 + B_ * C_;      // B*C
  float* hconst = std0 + B_ * C_;       // B*H
  float* pooled = hconst + B_ * H_;     // B*2C
  float* wl1    = pooled + B_ * C2_;    // C
  float* ps0    = wl1 + C_;             // B*NT*C each:
  float* ps1    = ps0 + B_ * NT_ * C_;
  float* ps2    = ps1 + B_ * NT_ * C_;
  float* h_pre  = ps2 + B_ * NT_ * C_;  // 2 x B*T*H fp32 (K-half partials)
  unsigned short* hlnT = (unsigned short*)(h_pre + 2 * (size_t)B_ * T_ * H_);  // B*T*H bf16

  k_g1_and_stats<<<dim3(7 * NG1_), dim3(256), 0, stream>>>(x, w1, mask, h_pre, mean0, std0);
  k_hconst_wl1<<<dim3(B_ * H_ / 4 + C_ / 4), dim3(256), 0, stream>>>(
      w1, b1, mean0, std0, w2, hconst, wl1);
  k_ln_epi<<<dim3(NTL_, B_), dim3(256), 0, stream>>>(h_pre, hconst, g1, be1, hlnT);
  k_gemm2_pool<<<dim3(C_ / 64, B_, NT_), dim3(256), 0, stream>>>(x, mask, w2, hlnT, wl1,
                                                                 ps0, ps1, ps2);
  k_pool_merge<<<dim3(B_ * C_ / 256), dim3(256), 0, stream>>>(ps0, ps1, ps2, pooled);
  k_final_ln<<<dim3(B_), dim3(256), 0, stream>>>(pooled, g2, be2, out);
}

// Round 13
// 150.063 us; speedup vs baseline: 1.1686x; 1.1686x over previous
//
#include <hip/hip_runtime.h>
#include <hip/hip_bf16.h>
#include <math.h>

constexpr int B_  = 16;
constexpr int C_  = 1536;
constexpr int T_  = 2000;
constexpr int H_  = 128;
constexpr int C3_ = 3 * C_;   // 4608
constexpr int C2_ = 2 * C_;   // 3072
constexpr int NT_ = 4;        // t-parts for gemm2 (512 t each)

typedef short bf8 __attribute__((ext_vector_type(8)));   // 8 bf16 (4 VGPR) MFMA A/B frag
typedef short bf4 __attribute__((ext_vector_type(4)));   // 4 bf16 (8B)
typedef float f4  __attribute__((ext_vector_type(4)));   // MFMA C/D frag

// fp32 -> bf16 RTNE (hardware cvt; compiler pairs into v_cvt_pk_bf16_f32)
__device__ inline unsigned short f2b(float f) {
  __bf16 h = (__bf16)f;
  return __builtin_bit_cast(unsigned short, h);
}

// ---------------- K1: masked per-(b,c) mean/std over T (one wave per row) ----
__global__ __launch_bounds__(256) void k_stats(
    const float* __restrict__ x, const float* __restrict__ mask,
    float* __restrict__ mean0, float* __restrict__ std0) {
  const int wave = threadIdx.x >> 6;
  const int lane = threadIdx.x & 63;
  const int row = blockIdx.x * 4 + wave;      // b*C + c
  const int b = row / C_;
  const float4* xr = (const float4*)(x + (size_t)row * T_);
  const float4* mr = (const float4*)(mask + (size_t)b * T_);
  float sm = 0.f, s1 = 0.f, s2 = 0.f;
  for (int i = lane; i < T_ / 4; i += 64) {
    float4 xv = xr[i];
    float4 mv = mr[i];
    sm += mv.x + mv.y + mv.z + mv.w;
    s1 += mv.x * xv.x + mv.y * xv.y + mv.z * xv.z + mv.w * xv.w;
    s2 += mv.x * xv.x * xv.x + mv.y * xv.y * xv.y + mv.z * xv.z * xv.z + mv.w * xv.w * xv.w;
  }
#pragma unroll
  for (int off = 32; off; off >>= 1) {
    sm += __shfl_xor(sm, off);
    s1 += __shfl_xor(s1, off);
    s2 += __shfl_xor(s2, off);
  }
  if (lane == 0) {
    float mean = s1 / sm;
    float var = s2 / sm - mean * mean;
    mean0[row] = mean;
    std0[row] = sqrtf(fmaxf(var, 1e-5f));
  }
}

// ---------------- K2: hconst GEMV + wl1 L1-norms in ONE launch ----------------
__global__ __launch_bounds__(256) void k_hconst_wl1(
    const float* __restrict__ w1, const float* __restrict__ b1,
    const float* __restrict__ mean0, const float* __restrict__ std0,
    const float* __restrict__ w2,
    float* __restrict__ hconst, float* __restrict__ wl1) {
  const int wave = threadIdx.x >> 6;
  const int lane = threadIdx.x & 63;
  if (blockIdx.x < B_ * H_ / 4) {
    const int idx = blockIdx.x * 4 + wave;      // b*H + h
    const int b = idx >> 7;
    const int h = idx & (H_ - 1);
    const float* wm  = w1 + (size_t)h * C3_ + C_;
    const float* wsd = wm + C_;
    const float* mn = mean0 + b * C_;
    const float* sd = std0 + b * C_;
    float s = 0.f;
    for (int c = lane; c < C_; c += 64)
      s += wm[c] * mn[c] + wsd[c] * sd[c];
#pragma unroll
    for (int off = 32; off; off >>= 1) s += __shfl_xor(s, off);
    if (lane == 0) hconst[idx] = s + b1[h];
  } else {
    const int c = (blockIdx.x - B_ * H_ / 4) * 4 + wave;
    const float* wr = w2 + (size_t)c * H_;
    float s = fabsf(wr[lane]) + fabsf(wr[lane + 64]);
#pragma unroll
    for (int off = 32; off; off >>= 1) s += __shfl_xor(s, off);
    if (lane == 0) wl1[c] = s;
  }
}

// ---------------- K3: MFMA GEMM1 (reg-B) + relu + LN(H) + tanh -> hlnT bf16 ---
// block 256 thr (4 waves), tile 128h x 64t; wave w owns t-slice w*16..+15.
// B-OPERAND DIRECT TO REGISTERS: MFMA B-frag layout (lane: k-group=l4, n=l15)
// is loaded straight from global x (8 dword loads, stride T) -- no B LDS, no
// transpose ds_writes (R12's 4.3M bank conflicts), no B ds_reads.
// A (w1) stays in LDS: 16KB dbuf, conflict-free measured layout (R3-R11).
__global__ __launch_bounds__(256) void k_gemm1_ln(
    const float* __restrict__ x, const float* __restrict__ w1,
    const float* __restrict__ hconst, const float* __restrict__ g1,
    const float* __restrict__ be1, unsigned short* __restrict__ hlnT) {
  __shared__ __align__(16) short As[2][128 * 32];
  const int b = blockIdx.y;
  const int t0 = blockIdx.x * 64;
  const int tid = threadIdx.x;
  const int lane = tid & 63;
  const int w = tid >> 6;
  const int l15 = lane & 15;
  const int l4 = lane >> 4;
  // this lane's t-column (clamped; t>=T_ columns produce garbage that is
  // never stored -- LN is per t-column so no contamination)
  const int tcl = min(t0 + w * 16 + l15, T_ - 1);
  const float* xcol = x + (size_t)b * C_ * T_ + tcl;

  float4 va[4];
  float xs0[8], xs1[8];

  f4 acc[8];
#pragma unroll
  for (int mi = 0; mi < 8; ++mi) { f4 z = {0.f, 0.f, 0.f, 0.f}; acc[mi] = z; }

#define G1_GLOADA(K0)                                                         \
  {                                                                           \
    _Pragma("unroll")                                                         \
    for (int q = 0; q < 4; ++q) {                                             \
      int idx = q * 256 + tid;                                                \
      int row = idx >> 3, j4 = idx & 7;                                       \
      va[q] = *(const float4*)(w1 + (size_t)row * C3_ + (K0) + j4 * 4);       \
    }                                                                         \
  }
#define G1_GLOADB(K0, XS)                                                     \
  {                                                                           \
    const float* xb = xcol + ((size_t)(K0) + l4 * 8) * T_;                    \
    _Pragma("unroll")                                                         \
    for (int j = 0; j < 8; ++j) XS[j] = xb[(size_t)j * T_];                   \
  }
#define G1_LSTOREA(BUF)                                                       \
  {                                                                           \
    _Pragma("unroll")                                                         \
    for (int q = 0; q < 4; ++q) {                                             \
      int idx = q * 256 + tid;                                                \
      int row = idx >> 3, j4 = idx & 7;                                       \
      int slot = (j4 >> 1) ^ ((row >> 2) & 3);                                \
      bf4 p;                                                                  \
      p[0] = (short)f2b(va[q].x); p[1] = (short)f2b(va[q].y);                 \
      p[2] = (short)f2b(va[q].z); p[3] = (short)f2b(va[q].w);                 \
      *(bf4*)&As[BUF][row * 32 + slot * 8 + (j4 & 1) * 4] = p;                \
    }                                                                         \
  }
// one K-step: prefetch A+B for step s+1, compute step s from regs+LDS[CUR]
#define G1_STEP(S, XSCUR, XSNXT, CUR)                                         \
  {                                                                           \
    if ((S) + 1 < NS) {                                                       \
      G1_GLOADA(((S) + 1) * 32);                                              \
      G1_GLOADB(((S) + 1) * 32, XSNXT);                                       \
    }                                                                         \
    bf8 bfr;                                                                  \
    _Pragma("unroll")                                                         \
    for (int j = 0; j < 8; ++j) bfr[j] = (short)f2b(XSCUR[j]);                \
    _Pragma("unroll")                                                         \
    for (int mi = 0; mi < 8; ++mi) {                                          \
      bf8 afr = *(const bf8*)&As[CUR][(mi * 16 + l15) * 32 + (l4 ^ fA) * 8];  \
      acc[mi] = __builtin_amdgcn_mfma_f32_16x16x32_bf16(afr, bfr, acc[mi], 0, 0, 0); \
    }                                                                         \
    if ((S) + 1 < NS) G1_LSTOREA(CUR ^ 1);                                    \
    __syncthreads();                                                          \
  }

  const int fA = (l15 >> 2) & 3;        // A-read swizzle term
  const int NS = C_ / 32;               // 48 K-steps

  G1_GLOADA(0);
  G1_GLOADB(0, xs0);
  G1_LSTOREA(0);
  __syncthreads();

  for (int sp = 0; sp < NS / 2; ++sp) {
    G1_STEP(2 * sp,     xs0, xs1, 0);
    G1_STEP(2 * sp + 1, xs1, xs0, 1);
  }

  // epilogue: +hconst, relu, LN over 128 h (per t-col), tanh, bf16 store
  const int t = t0 + w * 16 + l15;
  float sum = 0.f, ssq = 0.f;
#pragma unroll
  for (int mi = 0; mi < 8; ++mi) {
    float4 h4 = *(const float4*)(hconst + b * H_ + mi * 16 + l4 * 4);
    const float* hp = (const float*)&h4;
#pragma unroll
    for (int reg = 0; reg < 4; ++reg) {
      float v = fmaxf(acc[mi][reg] + hp[reg], 0.f);
      acc[mi][reg] = v;
      sum += v;
      ssq += v * v;
    }
  }
  sum += __shfl_xor(sum, 16); sum += __shfl_xor(sum, 32);
  ssq += __shfl_xor(ssq, 16); ssq += __shfl_xor(ssq, 32);
  const float mean = sum * (1.f / 128.f);
  const float rstd = rsqrtf(ssq * (1.f / 128.f) - mean * mean + 1e-5f);
  if (t < T_) {
    unsigned short* dst = hlnT + ((size_t)b * T_ + t) * H_;
#pragma unroll
    for (int mi = 0; mi < 8; ++mi) {
      float4 g4 = *(const float4*)(g1 + mi * 16 + l4 * 4);
      float4 e4 = *(const float4*)(be1 + mi * 16 + l4 * 4);
      const float* gp = (const float*)&g4;
      const float* ep = (const float*)&e4;
      bf4 p;
#pragma unroll
      for (int reg = 0; reg < 4; ++reg) {
        float o = tanhf((acc[mi][reg] - mean) * rstd * gp[reg] + ep[reg]);
        p[reg] = (short)f2b(o);
      }
      *(bf4*)&dst[mi * 16 + l4 * 4] = p;
    }
  }
}

// ---------------- K4: MFMA GEMM2 (alpha=w2@hln) + FIXED-MAX softmax + pooling -
// grid (24 c-tiles of 64, B, NT parts); part owns t in [part*512, +512).
// A-operand (w2 rows) in REGISTERS; LDS = Hs 32KB only.
// e = exp(alpha - wl1[c]): no running max, no rescale; Mc cancels in s1/s0.
__global__ __launch_bounds__(256) void k_gemm2_pool(
    const float* __restrict__ x, const float* __restrict__ mask,
    const float* __restrict__ w2, const unsigned short* __restrict__ hlnT,
    const float* __restrict__ wl1,
    float* __restrict__ ps0, float* __restrict__ ps1, float* __restrict__ ps2) {
  __shared__ __align__(16) short Hs[2][64 * 128];   // [t][h] swizzled, 2x16KB
  const int b = blockIdx.y;
  const int c0 = blockIdx.x * 64;
  const int part = blockIdx.z;
  const int tb = part * 512;
  const int te = min(tb + 512, T_);
  const int tid = threadIdx.x;
  const int lane = tid & 63;
  const int w = tid >> 6;
  const int l15 = lane & 15;
  const int l4 = lane >> 4;

  // A-frags in registers: af[ks] = w2[c0+w*16+l15][(ks*4+l4)*8 ..+8]
  bf8 af[4];
#pragma unroll
  for (int ks = 0; ks < 4; ++ks) {
    const float* src = w2 + (size_t)(c0 + w * 16 + l15) * H_ + (ks * 4 + l4) * 8;
    float4 v0 = *(const float4*)src;
    float4 v1 = *(const float4*)(src + 4);
    bf8 p;
    p[0] = (short)f2b(v0.x); p[1] = (short)f2b(v0.y);
    p[2] = (short)f2b(v0.z); p[3] = (short)f2b(v0.w);
    p[4] = (short)f2b(v1.x); p[5] = (short)f2b(v1.y);
    p[6] = (short)f2b(v1.z); p[7] = (short)f2b(v1.w);
    af[ks] = p;
  }

  // static per-row logit bound Mc (exp arg <= 0, never overflows)
  float Mc[4];
  {
    float4 m4 = *(const float4*)(wl1 + c0 + w * 16 + l4 * 4);
    Mc[0] = m4.x; Mc[1] = m4.y; Mc[2] = m4.z; Mc[3] = m4.w;
  }

  float s0[4], s1[4], s2[4];
#pragma unroll
  for (int r = 0; r < 4; ++r) { s0[r] = 0.f; s1[r] = 0.f; s2[r] = 0.f; }

  bf8 hreg[4];
#define G2_HLOAD(T0)                                                          \
  {                                                                           \
    _Pragma("unroll")                                                         \
    for (int q = 0; q < 4; ++q) {                                             \
      int idx = q * 256 + tid;                                                \
      int row = idx >> 4, slot = idx & 15;                                    \
      int t = (T0) + row;                                                     \
      if (t > T_ - 1) t = T_ - 1;                                             \
      hreg[q] = *(const bf8*)(hlnT + ((size_t)b * T_ + t) * H_ + slot * 8);   \
    }                                                                         \
  }
#define G2_HSTORE(BUF)                                                        \
  {                                                                           \
    _Pragma("unroll")                                                         \
    for (int q = 0; q < 4; ++q) {                                             \
      int idx = q * 256 + tid;                                                \
      int row = idx >> 4, slot = idx & 15;                                    \
      *(bf8*)&Hs[BUF][row * 128 + (slot ^ (row & 15)) * 8] = hreg[q];         \
    }                                                                         \
  }

  G2_HLOAD(tb);
  G2_HSTORE(0);
  __syncthreads();

  const int NCH = (te - tb + 63) / 64;   // <= 8
  for (int ch = 0; ch < NCH; ++ch) {
    const int t0 = tb + ch * 64;
    const int cur = ch & 1;
    if (ch + 1 < NCH) G2_HLOAD(t0 + 64);

    // issue-early: mask + x loads for this chunk, consumed after MFMA
    float mk[4];
    int tcol[4];
#pragma unroll
    for (int nj = 0; nj < 4; ++nj) {
      int t = t0 + nj * 16 + l15;
      tcol[nj] = (t < T_) ? t : (T_ - 1);
      mk[nj] = (t < T_) ? mask[(size_t)b * T_ + t] : 0.f;
    }
    float xv[4][4];
#pragma unroll
    for (int reg = 0; reg < 4; ++reg) {
      const int c = c0 + w * 16 + l4 * 4 + reg;
      const float* xrow = x + ((size_t)(b * C_ + c)) * T_;
#pragma unroll
      for (int nj = 0; nj < 4; ++nj) xv[reg][nj] = xrow[tcol[nj]];
    }

    f4 acc[4];
#pragma unroll
    for (int nj = 0; nj < 4; ++nj) { f4 z = {0.f, 0.f, 0.f, 0.f}; acc[nj] = z; }

#pragma unroll
    for (int ks = 0; ks < 4; ++ks) {
      const int sw = (ks * 4 + l4) ^ l15;   // row&15 == l15 for B rows
      bf8 bb[4];
#pragma unroll
      for (int nj = 0; nj < 4; ++nj)
        bb[nj] = *(const bf8*)&Hs[cur][(nj * 16 + l15) * 128 + sw * 8];
#pragma unroll
      for (int nj = 0; nj < 4; ++nj)
        acc[nj] = __builtin_amdgcn_mfma_f32_16x16x32_bf16(af[ks], bb[nj], acc[nj], 0, 0, 0);
    }

    // epilogue: fixed-max exp + pooled partial sums (no serial chain)
#pragma unroll
    for (int reg = 0; reg < 4; ++reg) {
      float a0 = s0[reg], a1 = s1[reg], a2 = s2[reg];
#pragma unroll
      for (int nj = 0; nj < 4; ++nj) {
        float e = (mk[nj] != 0.f) ? __expf(acc[nj][reg] - Mc[reg]) : 0.f;
        float xvv = xv[reg][nj];
        a0 += e; a1 += e * xvv; a2 += e * xvv * xvv;
      }
      s0[reg] = a0; s1[reg] = a1; s2[reg] = a2;
    }

    // HSTORE after the epilogue: the epilogue VALU hides this iter's HLOAD
    // latency; buffer cur^1 was drained at the previous iteration's barrier.
    if (ch + 1 < NCH) G2_HSTORE(cur ^ 1);
    __syncthreads();
  }

  // merge the 16 lanes (t-cols) of each row group: plain adds
#pragma unroll
  for (int off = 1; off < 16; off <<= 1) {
#pragma unroll
    for (int r = 0; r < 4; ++r) {
      s0[r] += __shfl_xor(s0[r], off);
      s1[r] += __shfl_xor(s1[r], off);
      s2[r] += __shfl_xor(s2[r], off);
    }
  }
  if (l15 == 0) {
#pragma unroll
    for (int reg = 0; reg < 4; ++reg) {
      const int c = c0 + w * 16 + l4 * 4 + reg;
      const size_t j = ((size_t)(b * NT_ + part)) * C_ + c;
      ps0[j] = s0[reg]; ps1[j] = s1[reg]; ps2[j] = s2[reg];
    }
  }
}

// ---------------- K4b: plain-sum the NT t-part partials -> pooled -------------
__global__ __launch_bounds__(256) void k_pool_merge(
    const float* __restrict__ ps0, const float* __restrict__ ps1,
    const float* __restrict__ ps2, float* __restrict__ pooled) {
  const int idx = blockIdx.x * 256 + threadIdx.x;   // b*C + c
  const int b = idx / C_;
  const int c = idx - b * C_;
  float s0 = 0.f, s1 = 0.f, s2 = 0.f;
#pragma unroll
  for (int p = 0; p < NT_; ++p) {
    const size_t j = ((size_t)(b * NT_ + p)) * C_ + c;
    s0 += ps0[j]; s1 += ps1[j]; s2 += ps2[j];
  }
  float mean = s1 / s0;
  float var = s2 / s0 - mean * mean;
  pooled[b * C2_ + c] = mean;
  pooled[b * C2_ + C_ + c] = sqrtf(fmaxf(var, 1e-5f));
}

// ---------------- K5: final LN over 2C channels per b -------------------------
__global__ __launch_bounds__(256) void k_final_ln(
    const float* __restrict__ pooled, const float* __restrict__ g2,
    const float* __restrict__ be2, float* __restrict__ out) {
  __shared__ float rs[8];
  const int b = blockIdx.x;
  const int tid = threadIdx.x;
  const int lane = tid & 63;
  const int wave = tid >> 6;
  const float* p = pooled + b * C2_;
  float s = 0.f, q = 0.f;
  for (int i = tid; i < C2_; i += 256) {
    float v = p[i];
    s += v;
    q += v * v;
  }
#pragma unroll
  for (int off = 32; off; off >>= 1) {
    s += __shfl_xor(s, off);
    q += __shfl_xor(q, off);
  }
  if (lane == 0) { rs[wave] = s; rs[4 + wave] = q; }
  __syncthreads();
  s = rs[0] + rs[1] + rs[2] + rs[3];
  q = rs[4] + rs[5] + rs[6] + rs[7];
  float mean = s * (1.f / C2_);
  float var = q * (1.f / C2_) - mean * mean;
  float rstd = rsqrtf(var + 1e-5f);
  for (int i = tid; i < C2_; i += 256)
    out[b * C2_ + i] = (p[i] - mean) * rstd * g2[i] + be2[i];
}

extern "C" void kernel_launch(void* const* d_in, const int* in_sizes, int n_in,
                              void* d_out, int out_size, void* d_ws, size_t ws_size,
                              hipStream_t stream) {
  const float* x    = (const float*)d_in[0];
  const float* mask = (const float*)d_in[1];
  const float* w1   = (const float*)d_in[2];
  const float* b1   = (const float*)d_in[3];
  const float* g1   = (const float*)d_in[4];
  const float* be1  = (const float*)d_in[5];
  const float* w2   = (const float*)d_in[6];
  // d_in[7] = b2: per-(b,c) constant on softmax logits -> softmax-invariant, dropped
  const float* g2   = (const float*)d_in[8];
  const float* be2  = (const float*)d_in[9];
  float* out = (float*)d_out;

  float* ws     = (float*)d_ws;
  float* mean0  = ws;                   // B*C
  float* std0   = mean0 + B_ * C_;      // B*C
  float* hconst = std0 + B_ * C_;       // B*H
  float* pooled = hconst + B_ * H_;     // B*2C
  float* wl1    = pooled + B_ * C2_;    // C
  float* ps0    = wl1 + C_;             // B*NT*C each:
  float* ps1    = ps0 + B_ * NT_ * C_;
  float* ps2    = ps1 + B_ * NT_ * C_;
  unsigned short* hlnT = (unsigned short*)(ps2 + B_ * NT_ * C_);  // B*T*H bf16

  k_stats<<<dim3(B_ * C_ / 4), dim3(256), 0, stream>>>(x, mask, mean0, std0);
  k_hconst_wl1<<<dim3(B_ * H_ / 4 + C_ / 4), dim3(256), 0, stream>>>(
      w1, b1, mean0, std0, w2, hconst, wl1);
  k_gemm1_ln<<<dim3((T_ + 63) / 64, B_), dim3(256), 0, stream>>>(x, w1, hconst, g1, be1, hlnT);
  k_gemm2_pool<<<dim3(C_ / 64, B_, NT_), dim3(256), 0, stream>>>(x, mask, w2, hlnT, wl1,
                                                                 ps0, ps1, ps2);
  k_pool_merge<<<dim3(B_ * C_ / 256), dim3(256), 0, stream>>>(ps0, ps1, ps2, pooled);
  k_final_ln<<<dim3(B_), dim3(256), 0, stream>>>(pooled, g2, be2, out);
}